// Round 1
// baseline (98.776 us; speedup 1.0000x reference)
//
#include <hip/hip_runtime.h>
#include <hip/hip_bf16.h>

// Problem constants (B,N,H,O) = (2,512,128,32)
#define NN 512
#define HH 128
#define OO 32

__device__ __forceinline__ float tanh_fast(float x) {
    // tanh(x) = 1 - 2/(exp(2x)+1); exact at +/-inf saturation, ~2ulp.
    float e = __expf(2.0f * x);
    return 1.0f - __fdividef(2.0f, e + 1.0f);
}

__device__ __forceinline__ float waveRedMax(float v) {
#pragma unroll
    for (int off = 32; off > 0; off >>= 1) v = fmaxf(v, __shfl_xor(v, off, 64));
    return v;
}
__device__ __forceinline__ float waveRedSum(float v) {
#pragma unroll
    for (int off = 32; off > 0; off >>= 1) v += __shfl_xor(v, off, 64);
    return v;
}

// ---------------------------------------------------------------------------
// K0: transpose weights into [k][h] layout so per-lane dot loads coalesce.
// Segments: WqT(16384) W1iT(16384) W1jT(16384) WkT(4096) W2T W3T W4T(16384 ea)
// ---------------------------------------------------------------------------
__global__ __launch_bounds__(256) void transpose_weights(
    const float* __restrict__ W1, const float* __restrict__ Wq,
    const float* __restrict__ Wk, const float* __restrict__ W2,
    const float* __restrict__ W3, const float* __restrict__ W4,
    float* __restrict__ WqT, float* __restrict__ W1iT, float* __restrict__ W1jT,
    float* __restrict__ WkT, float* __restrict__ W2T, float* __restrict__ W3T,
    float* __restrict__ W4T) {
    int tid = blockIdx.x * 256 + threadIdx.x;
    if (tid < 16384) { int k = tid >> 7, h = tid & 127; WqT[tid] = Wq[h * 128 + k]; return; }
    tid -= 16384;
    if (tid < 16384) { int k = tid >> 7, h = tid & 127; W1iT[tid] = W1[h * 256 + k]; return; }
    tid -= 16384;
    if (tid < 16384) { int k = tid >> 7, h = tid & 127; W1jT[tid] = W1[h * 256 + 128 + k]; return; }
    tid -= 16384;
    if (tid < 4096)  { int o = tid >> 7, h = tid & 127; WkT[tid] = Wk[h * 32 + o]; return; }
    tid -= 4096;
    if (tid < 16384) { int k = tid >> 7, h = tid & 127; W2T[tid] = W2[h * 128 + k]; return; }
    tid -= 16384;
    if (tid < 16384) { int k = tid >> 7, h = tid & 127; W3T[tid] = W3[h * 128 + k]; return; }
    tid -= 16384;
    if (tid < 16384) { int k = tid >> 7, h = tid & 127; W4T[tid] = W4[h * 128 + k]; return; }
}

// ---------------------------------------------------------------------------
// K1: prep — per row r: q = z@Wq.T+bq ; ziB = z@W1i.T+b1 ; zj = z@W1j.T ;
//           k = s_t@Wk.T+bk stored TRANSPOSED as kT[b][h][j] for coalesced P1.
// 4 rows per block, 256 threads (thread-half owns 2 rows).
// ---------------------------------------------------------------------------
__global__ __launch_bounds__(256) void prep_kernel(
    const float* __restrict__ z, const float* __restrict__ s_t,
    const float* __restrict__ bq, const float* __restrict__ b1,
    const float* __restrict__ bk,
    const float* __restrict__ WqT, const float* __restrict__ W1iT,
    const float* __restrict__ W1jT, const float* __restrict__ WkT,
    float* __restrict__ qo, float* __restrict__ kT,
    float* __restrict__ ziB, float* __restrict__ zjo) {
    __shared__ float zrow[4][HH];
    __shared__ float srow[4][OO];
    int t = threadIdx.x;
    int r0 = blockIdx.x * 4;
    for (int idx = t; idx < 4 * HH; idx += 256)
        zrow[idx >> 7][idx & 127] = z[(size_t)r0 * HH + idx];
    for (int idx = t; idx < 4 * OO; idx += 256)
        srow[idx >> 5][idx & 31] = s_t[(size_t)r0 * OO + idx];
    __syncthreads();

    int h = t & 127, half = t >> 7;
    int ra = half * 2, rb = ra + 1;
    float aq0 = 0, aq1 = 0, ai0 = 0, ai1 = 0, aj0 = 0, aj1 = 0;
#pragma unroll 4
    for (int k = 0; k < HH; k++) {
        float wq = WqT[k * HH + h], wi = W1iT[k * HH + h], wj = W1jT[k * HH + h];
        float z0 = zrow[ra][k], z1 = zrow[rb][k];
        aq0 = fmaf(z0, wq, aq0); aq1 = fmaf(z1, wq, aq1);
        ai0 = fmaf(z0, wi, ai0); ai1 = fmaf(z1, wi, ai1);
        aj0 = fmaf(z0, wj, aj0); aj1 = fmaf(z1, wj, aj1);
    }
    float ak0 = 0, ak1 = 0;
#pragma unroll 4
    for (int o = 0; o < OO; o++) {
        float wk = WkT[o * HH + h];
        ak0 = fmaf(srow[ra][o], wk, ak0); ak1 = fmaf(srow[rb][o], wk, ak1);
    }
    float vbq = bq[h], vb1 = b1[h], vbk = bk[h];
    int ga = r0 + ra, gb = r0 + rb;
    qo[(size_t)ga * HH + h] = aq0 + vbq;  qo[(size_t)gb * HH + h] = aq1 + vbq;
    ziB[(size_t)ga * HH + h] = ai0 + vb1; ziB[(size_t)gb * HH + h] = ai1 + vb1;
    zjo[(size_t)ga * HH + h] = aj0;       zjo[(size_t)gb * HH + h] = aj1;
    int ba = ga >> 9, ja = ga & 511;
    kT[((size_t)ba * HH + h) * NN + ja] = ak0 + vbk;
    int bb = gb >> 9, jb = gb & 511;
    kT[((size_t)bb * HH + h) * NN + jb] = ak1 + vbk;
}

// ---------------------------------------------------------------------------
// K2: mega — per block: 4 attention rows (b, ii0..ii0+3).
//   P1 scores (coalesced kT reads) -> P2 masked softmax (shuffle+LDS reduce)
//   P3 U = sum_j attn * tanh(ziB + zj)   [the 67M-tanh core]
//   P4-P6 row-local tail: agg=U@W2.T+b2 ; h1=tanh(agg@W3.T+b3) ; out=h1@W4.T+b4
// ---------------------------------------------------------------------------
__global__ __launch_bounds__(512) void mega_kernel(
    const float* __restrict__ qi, const float* __restrict__ kT,
    const float* __restrict__ a2g, const float* __restrict__ zj,
    const float* __restrict__ W2T, const float* __restrict__ W3T,
    const float* __restrict__ W4T,
    const float* __restrict__ b2, const float* __restrict__ b3,
    const float* __restrict__ b4, float* __restrict__ out) {
    __shared__ float q2[4][HH];
    __shared__ float a2[4][HH];
    __shared__ float attnL[4][NN];
    __shared__ float U2[4][HH];
    __shared__ float v2[4][HH];
    __shared__ float red[8];

    int t = threadIdx.x;
    int b = blockIdx.x >> 7;            // 128 blocks per batch
    int ii0 = (blockIdx.x & 127) * 4;
    int gr0 = b * NN + ii0;

    ((float*)q2)[t] = qi[(size_t)gr0 * HH + t];
    ((float*)a2)[t] = a2g[(size_t)gr0 * HH + t];
    __syncthreads();

    // ---- P1: scores for j = t, all 4 rows ----
    {
        int j = t;
        const float* kb = kT + (size_t)b * HH * NN + j;
        float s0 = 0, s1 = 0, s2 = 0, s3 = 0;
#pragma unroll 8
        for (int h = 0; h < HH; h++) {
            float kv = kb[(size_t)h * NN];
            s0 = fmaf(q2[0][h], kv, s0); s1 = fmaf(q2[1][h], kv, s1);
            s2 = fmaf(q2[2][h], kv, s2); s3 = fmaf(q2[3][h], kv, s3);
        }
        const float sc = 0.08838834764831845f;  // 1/sqrt(128)
        s0 *= sc; s1 *= sc; s2 *= sc; s3 *= sc;
        if (j == ii0)     s0 = -1e30f;
        if (j == ii0 + 1) s1 = -1e30f;
        if (j == ii0 + 2) s2 = -1e30f;
        if (j == ii0 + 3) s3 = -1e30f;
        attnL[0][j] = s0; attnL[1][j] = s1; attnL[2][j] = s2; attnL[3][j] = s3;
    }
    __syncthreads();

    // ---- P2: softmax per row ----
    int lane = t & 63, wid = t >> 6;
    for (int r = 0; r < 4; r++) {
        float s = attnL[r][t];
        float m = waveRedMax(s);
        if (lane == 0) red[wid] = m;
        __syncthreads();
        float mm = red[0];
#pragma unroll
        for (int w = 1; w < 8; w++) mm = fmaxf(mm, red[w]);
        __syncthreads();
        float e = __expf(s - mm);
        float ps = waveRedSum(e);
        if (lane == 0) red[wid] = ps;
        __syncthreads();
        float S = red[0];
#pragma unroll
        for (int w = 1; w < 8; w++) S += red[w];
        float inv = __fdividef(1.0f, S);
        attnL[r][t] = e * inv;
        __syncthreads();
    }

    // ---- P3: U[r][h] = sum_j attn[r][j] * tanh(ziB[r][h] + zj[j][h]) ----
    int h = t & 127, r = t >> 7;
    {
        float a = a2[r][h];
        const float* zb = zj + (size_t)b * NN * HH + h;
        float u = 0.0f;
#pragma unroll 8
        for (int j = 0; j < NN; j++) {
            float w = attnL[r][j];
            float x = a + zb[(size_t)j * HH];
            u = fmaf(w, tanh_fast(x), u);
        }
        U2[r][h] = u;
    }
    __syncthreads();

    // ---- P4: agg = U@W2.T + b2 ----
    {
        float acc = 0;
#pragma unroll 4
        for (int k = 0; k < HH; k++) acc = fmaf(U2[r][k], W2T[k * HH + h], acc);
        v2[r][h] = acc + b2[h];
    }
    __syncthreads();
    // ---- P5: h1 = tanh(agg@W3.T + b3) ----
    {
        float acc = 0;
#pragma unroll 4
        for (int k = 0; k < HH; k++) acc = fmaf(v2[r][k], W3T[k * HH + h], acc);
        U2[r][h] = tanh_fast(acc + b3[h]);
    }
    __syncthreads();
    // ---- P6: out = h1@W4.T + b4 ----
    {
        float acc = 0;
#pragma unroll 4
        for (int k = 0; k < HH; k++) acc = fmaf(U2[r][k], W4T[k * HH + h], acc);
        out[(size_t)(gr0 + r) * HH + h] = acc + b4[h];
    }
}

extern "C" void kernel_launch(void* const* d_in, const int* in_sizes, int n_in,
                              void* d_out, int out_size, void* d_ws, size_t ws_size,
                              hipStream_t stream) {
    const float* z   = (const float*)d_in[0];
    const float* s_t = (const float*)d_in[1];
    const float* W1  = (const float*)d_in[2];
    const float* b1  = (const float*)d_in[3];
    const float* W2  = (const float*)d_in[4];
    const float* b2  = (const float*)d_in[5];
    const float* Wq  = (const float*)d_in[6];
    const float* bq  = (const float*)d_in[7];
    const float* Wk  = (const float*)d_in[8];
    const float* bk  = (const float*)d_in[9];
    const float* W3  = (const float*)d_in[10];
    const float* b3  = (const float*)d_in[11];
    const float* W4  = (const float*)d_in[12];
    const float* b4  = (const float*)d_in[13];
    float* out = (float*)d_out;

    float* ws   = (float*)d_ws;
    float* q    = ws;                 // 131072
    float* kT   = ws + 131072;        // 131072  ([b][h][j])
    float* ziB  = ws + 262144;        // 131072
    float* zj   = ws + 393216;        // 131072
    float* WqT  = ws + 524288;        // 16384
    float* W1iT = WqT + 16384;
    float* W1jT = W1iT + 16384;
    float* WkT  = W1jT + 16384;       // 4096
    float* W2T  = WkT + 4096;
    float* W3T  = W2T + 16384;
    float* W4T  = W3T + 16384;

    hipLaunchKernelGGL(transpose_weights, dim3(400), dim3(256), 0, stream,
                       W1, Wq, Wk, W2, W3, W4, WqT, W1iT, W1jT, WkT, W2T, W3T, W4T);
    hipLaunchKernelGGL(prep_kernel, dim3(256), dim3(256), 0, stream,
                       z, s_t, bq, b1, bk, WqT, W1iT, W1jT, WkT, q, kT, ziB, zj);
    hipLaunchKernelGGL(mega_kernel, dim3(256), dim3(512), 0, stream,
                       q, kT, ziB, zj, W2T, W3T, W4T, b2, b3, b4, out);
}

// Round 2
// 58.311 us; speedup vs baseline: 1.6939x; 1.6939x over previous
//
#include <hip/hip_runtime.h>
#include <hip/hip_bf16.h>

// Problem constants (B,N,H,O) = (2,512,128,32)
#define NN 512
#define HH 128
#define OO 32

// 2*log2(e): tanh(x) = 1 - 2/(2^(KL*x_a)*2^(KL*x_b)+1) with x = x_a+x_b
#define KL 2.8853900817779268f

__device__ __forceinline__ float vexp2(float x) {   // 2^x via v_exp_f32
    float r; asm("v_exp_f32 %0, %1" : "=v"(r) : "v"(x)); return r;
}
__device__ __forceinline__ float vrcp(float x) {    // 1/x via v_rcp_f32
    float r; asm("v_rcp_f32 %0, %1" : "=v"(r) : "v"(x)); return r;
}
__device__ __forceinline__ float tanh_fast(float x) {
    float e = vexp2(KL * x);
    return 1.0f - 2.0f * vrcp(e + 1.0f);
}

__device__ __forceinline__ float waveRedMax(float v) {
#pragma unroll
    for (int off = 32; off > 0; off >>= 1) v = fmaxf(v, __shfl_xor(v, off, 64));
    return v;
}
__device__ __forceinline__ float waveRedSum(float v) {
#pragma unroll
    for (int off = 32; off > 0; off >>= 1) v += __shfl_xor(v, off, 64);
    return v;
}

// ---------------------------------------------------------------------------
// K0: transpose weights into [k][h] layout so per-lane dot loads coalesce.
// ---------------------------------------------------------------------------
__global__ __launch_bounds__(256) void transpose_weights(
    const float* __restrict__ W1, const float* __restrict__ Wq,
    const float* __restrict__ Wk, const float* __restrict__ W2,
    const float* __restrict__ W3, const float* __restrict__ W4,
    float* __restrict__ WqT, float* __restrict__ W1iT, float* __restrict__ W1jT,
    float* __restrict__ WkT, float* __restrict__ W2T, float* __restrict__ W3T,
    float* __restrict__ W4T) {
    int tid = blockIdx.x * 256 + threadIdx.x;
    if (tid < 16384) { int k = tid >> 7, h = tid & 127; WqT[tid] = Wq[h * 128 + k]; return; }
    tid -= 16384;
    if (tid < 16384) { int k = tid >> 7, h = tid & 127; W1iT[tid] = W1[h * 256 + k]; return; }
    tid -= 16384;
    if (tid < 16384) { int k = tid >> 7, h = tid & 127; W1jT[tid] = W1[h * 256 + 128 + k]; return; }
    tid -= 16384;
    if (tid < 4096)  { int o = tid >> 7, h = tid & 127; WkT[tid] = Wk[h * 32 + o]; return; }
    tid -= 4096;
    if (tid < 16384) { int k = tid >> 7, h = tid & 127; W2T[tid] = W2[h * 128 + k]; return; }
    tid -= 16384;
    if (tid < 16384) { int k = tid >> 7, h = tid & 127; W3T[tid] = W3[h * 128 + k]; return; }
    tid -= 16384;
    if (tid < 16384) { int k = tid >> 7, h = tid & 127; W4T[tid] = W4[h * 128 + k]; return; }
}

// ---------------------------------------------------------------------------
// K1: prep — per row: q = z@Wq.T+bq ; Ezi = 2^(KL*(z@W1i.T+b1)) ;
//     Ezj = 2^(KL*(z@W1j.T)) ; k = s_t@Wk.T+bk stored transposed kT[b][h][j].
// ---------------------------------------------------------------------------
__global__ __launch_bounds__(256) void prep_kernel(
    const float* __restrict__ z, const float* __restrict__ s_t,
    const float* __restrict__ bq, const float* __restrict__ b1,
    const float* __restrict__ bk,
    const float* __restrict__ WqT, const float* __restrict__ W1iT,
    const float* __restrict__ W1jT, const float* __restrict__ WkT,
    float* __restrict__ qo, float* __restrict__ kT,
    float* __restrict__ Ezi, float* __restrict__ Ezj) {
    __shared__ float zrow[4][HH];
    __shared__ float srow[4][OO];
    int t = threadIdx.x;
    int r0 = blockIdx.x * 4;
    for (int idx = t; idx < 4 * HH; idx += 256)
        zrow[idx >> 7][idx & 127] = z[(size_t)r0 * HH + idx];
    for (int idx = t; idx < 4 * OO; idx += 256)
        srow[idx >> 5][idx & 31] = s_t[(size_t)r0 * OO + idx];
    __syncthreads();

    int h = t & 127, half = t >> 7;
    int ra = half * 2, rb = ra + 1;
    float aq0 = 0, aq1 = 0, ai0 = 0, ai1 = 0, aj0 = 0, aj1 = 0;
#pragma unroll 4
    for (int k = 0; k < HH; k++) {
        float wq = WqT[k * HH + h], wi = W1iT[k * HH + h], wj = W1jT[k * HH + h];
        float z0 = zrow[ra][k], z1 = zrow[rb][k];
        aq0 = fmaf(z0, wq, aq0); aq1 = fmaf(z1, wq, aq1);
        ai0 = fmaf(z0, wi, ai0); ai1 = fmaf(z1, wi, ai1);
        aj0 = fmaf(z0, wj, aj0); aj1 = fmaf(z1, wj, aj1);
    }
    float ak0 = 0, ak1 = 0;
#pragma unroll 4
    for (int o = 0; o < OO; o++) {
        float wk = WkT[o * HH + h];
        ak0 = fmaf(srow[ra][o], wk, ak0); ak1 = fmaf(srow[rb][o], wk, ak1);
    }
    float vbq = bq[h], vb1 = b1[h], vbk = bk[h];
    int ga = r0 + ra, gb = r0 + rb;
    qo[(size_t)ga * HH + h] = aq0 + vbq;  qo[(size_t)gb * HH + h] = aq1 + vbq;
    Ezi[(size_t)ga * HH + h] = vexp2(KL * (ai0 + vb1));
    Ezi[(size_t)gb * HH + h] = vexp2(KL * (ai1 + vb1));
    Ezj[(size_t)ga * HH + h] = vexp2(KL * aj0);
    Ezj[(size_t)gb * HH + h] = vexp2(KL * aj1);
    int ba = ga >> 9, ja = ga & 511;
    kT[((size_t)ba * HH + h) * NN + ja] = ak0 + vbk;
    int bb = gb >> 9, jb = gb & 511;
    kT[((size_t)bb * HH + h) * NN + jb] = ak1 + vbk;
}

// ---------------------------------------------------------------------------
// K2: fused — 1024 threads, 4 attention rows per block (256 blocks).
//   B: scores (thread = (rowpair, j), shares kT col between 2 rows)
//   C: masked softmax on registers (wave shuffle + LDS cross-wave)
//   D: acc[r] += attn * rcp(fma(Ezi, Ezj, 1))  [2 VALU + 1 trans / element]
//      U = 1 - 2*acc  (softmax rows sum to 1)
//   E: row-local tail GEMVs, k-sliced across thread halves.
// ---------------------------------------------------------------------------
__global__ __launch_bounds__(1024) void fused_kernel(
    const float* __restrict__ qi, const float* __restrict__ kT,
    const float* __restrict__ Ezi, const float* __restrict__ Ezj,
    const float* __restrict__ W2T, const float* __restrict__ W3T,
    const float* __restrict__ W4T,
    const float* __restrict__ b2, const float* __restrict__ b3,
    const float* __restrict__ b4, float* __restrict__ out) {
    __shared__ float q4[4][HH];          // q rows; later h1 ping buffer
    __shared__ float c4[4][HH];          // Ezi rows; later agg buffer
    __shared__ float attnL[4][NN];
    __shared__ float part[8][4][HH];     // j-slice partials; later tail partials
    __shared__ float UL[4][HH];
    __shared__ float redA[16], redB[16];

    int t = threadIdx.x;
    int b = blockIdx.x >> 7;
    int i0 = (blockIdx.x & 127) * 4;
    int gr0 = b * NN + i0;

    if (t < 512) ((float*)q4)[t] = qi[(size_t)gr0 * HH + t];
    else         ((float*)c4)[t - 512] = Ezi[(size_t)gr0 * HH + (t - 512)];
    __syncthreads();

    // ---- B: scores ----
    int j = t & 511, rp = t >> 9;
    int lr0 = rp * 2, lr1 = lr0 + 1;
    float s0 = 0, s1 = 0;
    {
        const float* kb = kT + (size_t)b * HH * NN + j;
#pragma unroll 8
        for (int h = 0; h < HH; h++) {
            float kv = kb[(size_t)h * NN];
            s0 = fmaf(q4[lr0][h], kv, s0);
            s1 = fmaf(q4[lr1][h], kv, s1);
        }
        const float sc = 0.08838834764831845f;  // 1/sqrt(128)
        s0 *= sc; s1 *= sc;
        if (j == i0 + lr0) s0 = -1e30f;
        if (j == i0 + lr1) s1 = -1e30f;
    }

    // ---- C: softmax (rows span 8 waves each) ----
    int lane = t & 63, w = t >> 6, wb = rp * 8;
    float m0 = waveRedMax(s0), m1 = waveRedMax(s1);
    if (lane == 0) { redA[w] = m0; redB[w] = m1; }
    __syncthreads();
    float mm0 = redA[wb], mm1 = redB[wb];
#pragma unroll
    for (int k = 1; k < 8; k++) { mm0 = fmaxf(mm0, redA[wb + k]); mm1 = fmaxf(mm1, redB[wb + k]); }
    float e0 = __expf(s0 - mm0), e1 = __expf(s1 - mm1);
    float p0 = waveRedSum(e0), p1 = waveRedSum(e1);
    __syncthreads();               // protect redA/redB reuse
    if (lane == 0) { redA[w] = p0; redB[w] = p1; }
    __syncthreads();
    float S0 = redA[wb], S1 = redB[wb];
#pragma unroll
    for (int k = 1; k < 8; k++) { S0 += redA[wb + k]; S1 += redB[wb + k]; }
    attnL[lr0][j] = e0 * __fdividef(1.0f, S0);
    attnL[lr1][j] = e1 * __fdividef(1.0f, S1);
    __syncthreads();

    // ---- D: tanh-core. thread = (qs, h); 64 j per thread, 4 rows share load ----
    int h = t & 127, qs = t >> 7;
    {
        float c0 = c4[0][h], c1 = c4[1][h], c2 = c4[2][h], c3 = c4[3][h];
        const float* zb = Ezj + (size_t)b * NN * HH + h;
        float a0 = 0, a1 = 0, a2 = 0, a3 = 0;
        int jbase = qs * 64;
        for (int jj = 0; jj < 64; jj += 4) {
            int j4 = jbase + jj;
            float4 w0 = *(const float4*)&attnL[0][j4];
            float4 w1 = *(const float4*)&attnL[1][j4];
            float4 w2 = *(const float4*)&attnL[2][j4];
            float4 w3 = *(const float4*)&attnL[3][j4];
            float E0 = zb[(size_t)(j4 + 0) * HH];
            float E1 = zb[(size_t)(j4 + 1) * HH];
            float E2 = zb[(size_t)(j4 + 2) * HH];
            float E3 = zb[(size_t)(j4 + 3) * HH];
            a0 = fmaf(w0.x, vrcp(fmaf(c0, E0, 1.0f)), a0);
            a1 = fmaf(w1.x, vrcp(fmaf(c1, E0, 1.0f)), a1);
            a2 = fmaf(w2.x, vrcp(fmaf(c2, E0, 1.0f)), a2);
            a3 = fmaf(w3.x, vrcp(fmaf(c3, E0, 1.0f)), a3);
            a0 = fmaf(w0.y, vrcp(fmaf(c0, E1, 1.0f)), a0);
            a1 = fmaf(w1.y, vrcp(fmaf(c1, E1, 1.0f)), a1);
            a2 = fmaf(w2.y, vrcp(fmaf(c2, E1, 1.0f)), a2);
            a3 = fmaf(w3.y, vrcp(fmaf(c3, E1, 1.0f)), a3);
            a0 = fmaf(w0.z, vrcp(fmaf(c0, E2, 1.0f)), a0);
            a1 = fmaf(w1.z, vrcp(fmaf(c1, E2, 1.0f)), a1);
            a2 = fmaf(w2.z, vrcp(fmaf(c2, E2, 1.0f)), a2);
            a3 = fmaf(w3.z, vrcp(fmaf(c3, E2, 1.0f)), a3);
            a0 = fmaf(w0.w, vrcp(fmaf(c0, E3, 1.0f)), a0);
            a1 = fmaf(w1.w, vrcp(fmaf(c1, E3, 1.0f)), a1);
            a2 = fmaf(w2.w, vrcp(fmaf(c2, E3, 1.0f)), a2);
            a3 = fmaf(w3.w, vrcp(fmaf(c3, E3, 1.0f)), a3);
        }
        part[qs][0][h] = a0; part[qs][1][h] = a1;
        part[qs][2][h] = a2; part[qs][3][h] = a3;
    }
    __syncthreads();
    if (t < 512) {
        int r = t >> 7, hh = t & 127;
        float s = 0;
#pragma unroll
        for (int q = 0; q < 8; q++) s += part[q][r][hh];
        UL[r][hh] = fmaf(-2.0f, s, 1.0f);   // U = 1 - 2*sum (softmax sums to 1)
    }
    __syncthreads();

    // ---- E: tail GEMVs, k sliced in halves (ks = t>>9) ----
    int r = (t >> 7) & 3, ks = t >> 9, k0 = ks * 64;
    {
        float acc = 0;
#pragma unroll 4
        for (int k = 0; k < 64; k++) acc = fmaf(UL[r][k0 + k], W2T[(k0 + k) * HH + h], acc);
        part[ks][r][h] = acc;
    }
    __syncthreads();
    if (t < 512) {
        int rr = t >> 7, hh = t & 127;
        c4[rr][hh] = part[0][rr][hh] + part[1][rr][hh] + b2[hh];
    }
    __syncthreads();
    {
        float acc = 0;
#pragma unroll 4
        for (int k = 0; k < 64; k++) acc = fmaf(c4[r][k0 + k], W3T[(k0 + k) * HH + h], acc);
        part[ks][r][h] = acc;
    }
    __syncthreads();
    if (t < 512) {
        int rr = t >> 7, hh = t & 127;
        q4[rr][hh] = tanh_fast(part[0][rr][hh] + part[1][rr][hh] + b3[hh]);
    }
    __syncthreads();
    {
        float acc = 0;
#pragma unroll 4
        for (int k = 0; k < 64; k++) acc = fmaf(q4[r][k0 + k], W4T[(k0 + k) * HH + h], acc);
        part[ks][r][h] = acc;
    }
    __syncthreads();
    if (t < 512) {
        int rr = t >> 7, hh = t & 127;
        out[(size_t)(gr0 + rr) * HH + hh] = part[0][rr][hh] + part[1][rr][hh] + b4[hh];
    }
}

extern "C" void kernel_launch(void* const* d_in, const int* in_sizes, int n_in,
                              void* d_out, int out_size, void* d_ws, size_t ws_size,
                              hipStream_t stream) {
    const float* z   = (const float*)d_in[0];
    const float* s_t = (const float*)d_in[1];
    const float* W1  = (const float*)d_in[2];
    const float* b1  = (const float*)d_in[3];
    const float* W2  = (const float*)d_in[4];
    const float* b2  = (const float*)d_in[5];
    const float* Wq  = (const float*)d_in[6];
    const float* bq  = (const float*)d_in[7];
    const float* Wk  = (const float*)d_in[8];
    const float* bk  = (const float*)d_in[9];
    const float* W3  = (const float*)d_in[10];
    const float* b3  = (const float*)d_in[11];
    const float* W4  = (const float*)d_in[12];
    const float* b4  = (const float*)d_in[13];
    float* out = (float*)d_out;

    float* ws   = (float*)d_ws;
    float* q    = ws;                 // 131072
    float* kT   = ws + 131072;        // 131072  ([b][h][j])
    float* Ezi  = ws + 262144;        // 131072
    float* Ezj  = ws + 393216;        // 131072
    float* WqT  = ws + 524288;        // 16384
    float* W1iT = WqT + 16384;
    float* W1jT = W1iT + 16384;
    float* WkT  = W1jT + 16384;       // 4096
    float* W2T  = WkT + 4096;
    float* W3T  = W2T + 16384;
    float* W4T  = W3T + 16384;

    hipLaunchKernelGGL(transpose_weights, dim3(400), dim3(256), 0, stream,
                       W1, Wq, Wk, W2, W3, W4, WqT, W1iT, W1jT, WkT, W2T, W3T, W4T);
    hipLaunchKernelGGL(prep_kernel, dim3(256), dim3(256), 0, stream,
                       z, s_t, bq, b1, bk, WqT, W1iT, W1jT, WkT, q, kT, Ezi, Ezj);
    hipLaunchKernelGGL(fused_kernel, dim3(256), dim3(1024), 0, stream,
                       q, kT, Ezi, Ezj, W2T, W3T, W4T, b2, b3, b4, out);
}